// Round 1
// baseline (71070.892 us; speedup 1.0000x reference)
//
#include <hip/hip_runtime.h>
#include <math.h>

// ---------------- problem dims ----------------
#define T_STEPS 512
#define BATCH   128
#define DIN     256     // D
#define HMAIN   1024    // H
#define HHYP    256     // HH
#define OUTN    128
#define EPS     1e-3f

// ---------------- workspace layout (floats) ----------------
#define SZ_WCAT1  (1024*1536)
#define SZ_WCOMB  (12*256*1024)
#define SZ_BCOMB  (8*1024)
#define SZ_BIAS1  (1024)
#define SZ_ACT1   (BATCH*1280)     // [h (1024) | hh (256)] per row
#define SZ_C      (BATCH*1024)
#define SZ_CH     (BATCH*256)
#define SZ_GPART  (4*BATCH*1024)   // split-K partials of hyper gates
#define SZ_SCB    (12*BATCH*1024)  // sc[0..7], badj[0..3]
#define SZ_XGHG   (2*BATCH*4096)   // xg then hg

#define OFF_WCAT1 0
#define OFF_WCOMB (OFF_WCAT1 + SZ_WCAT1)
#define OFF_BCOMB (OFF_WCOMB + SZ_WCOMB)
#define OFF_BIAS1 (OFF_BCOMB + SZ_BCOMB)
#define OFF_ACT1  (OFF_BIAS1 + SZ_BIAS1)
#define OFF_C     (OFF_ACT1 + SZ_ACT1)
#define OFF_CH    (OFF_C + SZ_C)
#define OFF_GPART (OFF_CH + SZ_CH)
#define OFF_SCB   (OFF_GPART + SZ_GPART)
#define OFF_XGHG  (OFF_SCB + SZ_SCB)

#define KSPLIT_NONE (1<<30)

__device__ __forceinline__ float sigm(float x){ return 1.f/(1.f + expf(-x)); }

// ---------------- generic fp32 tiled GEMM device function ----------------
// tile 32(M) x 64(N), KT=32, 128 threads, 4x4 micro-tile.
// A is row-major (M x K) possibly split at global-k == ksplit between A1/A2.
// B layout: b_nk=1 -> B[n*ldb + k] (weights stored (N,K));
//           b_nk=0 -> B[k*ldb + n] (weights stored (K,N)).
#define BM 32
#define BN 64
#define KT 32

__device__ void gemm_dev(const float* __restrict__ A1, int lda1, int ksplit,
                         const float* __restrict__ A2, int lda2,
                         const float* __restrict__ Bp, int ldb, int b_nk,
                         const float* __restrict__ bias,
                         float* __restrict__ C, int ldc,
                         int K, int k0, int mtile, int ntile)
{
    __shared__ __align__(16) float As[KT][BM+4];  // [k][m], padded
    __shared__ __align__(16) float Bs[KT][BN+4];  // [k][n], padded
    const int tid = threadIdx.x;          // 128 threads
    const int mt = tid >> 4;              // 0..7
    const int nt = tid & 15;              // 0..15
    const int m0g = mtile*BM, n0g = ntile*BN;

    float acc[4][4];
    #pragma unroll
    for (int i=0;i<4;++i)
        #pragma unroll
        for (int j=0;j<4;++j) acc[i][j]=0.f;

    for (int kt = 0; kt < K; kt += KT) {
        __syncthreads();
        // A tile: BM*KT = 1024 elems, 8 per thread, coalesced along k
        #pragma unroll
        for (int i=0;i<8;++i){
            int e = tid + i*128;
            int m = e >> 5, k = e & 31;
            int gk = k0 + kt + k;
            int gm = m0g + m;
            float v = (gk < ksplit) ? A1[(size_t)gm*lda1 + gk]
                                    : A2[(size_t)gm*lda2 + (gk - ksplit)];
            As[k][m] = v;
        }
        // B tile: KT*BN = 2048 elems, 16 per thread
        if (b_nk) {
            #pragma unroll
            for (int i=0;i<16;++i){
                int e = tid + i*128;
                int n = e >> 5, k = e & 31;
                Bs[k][n] = Bp[(size_t)(n0g + n)*ldb + (k0 + kt + k)];
            }
        } else {
            #pragma unroll
            for (int i=0;i<16;++i){
                int e = tid + i*128;
                int k = e >> 6, n = e & 63;
                Bs[k][n] = Bp[(size_t)(k0 + kt + k)*ldb + (n0g + n)];
            }
        }
        __syncthreads();
        #pragma unroll
        for (int k=0;k<KT;++k){
            float4 av = *(const float4*)(&As[k][4*mt]);
            float4 bv = *(const float4*)(&Bs[k][4*nt]);
            acc[0][0] += av.x*bv.x; acc[0][1] += av.x*bv.y; acc[0][2] += av.x*bv.z; acc[0][3] += av.x*bv.w;
            acc[1][0] += av.y*bv.x; acc[1][1] += av.y*bv.y; acc[1][2] += av.y*bv.z; acc[1][3] += av.y*bv.w;
            acc[2][0] += av.z*bv.x; acc[2][1] += av.z*bv.y; acc[2][2] += av.z*bv.z; acc[2][3] += av.z*bv.w;
            acc[3][0] += av.w*bv.x; acc[3][1] += av.w*bv.y; acc[3][2] += av.w*bv.z; acc[3][3] += av.w*bv.w;
        }
    }
    #pragma unroll
    for (int i=0;i<4;++i){
        int gm = m0g + 4*mt + i;
        #pragma unroll
        for (int j=0;j<4;++j){
            int gn = n0g + 4*nt + j;
            float v = acc[i][j];
            if (bias) v += bias[gn];
            C[(size_t)gm*ldc + gn] = v;
        }
    }
}

// ---------------- prep kernels (run once per call) ----------------
// Wcat1[n, 0:1280] = hyp_Wx[n,:]; Wcat1[n, 1280:1536] = hyp_Wh[n,:]
// bias1 = hyp_bx + hyp_bh; zero act1 (h,hh), c, ch.
__global__ __launch_bounds__(256) void k_prep_misc(
    const float* __restrict__ hyp_Wx, const float* __restrict__ hyp_Wh,
    const float* __restrict__ hyp_bx, const float* __restrict__ hyp_bh,
    float* __restrict__ ws)
{
    size_t i = (size_t)blockIdx.x*256 + threadIdx.x;
    if (i < (size_t)SZ_WCAT1) {
        int n = (int)(i / 1536), k = (int)(i % 1536);
        ws[OFF_WCAT1 + i] = (k < 1280) ? hyp_Wx[(size_t)n*1280 + k]
                                       : hyp_Wh[(size_t)n*256 + (k-1280)];
        return;
    }
    i -= SZ_WCAT1;
    if (i < SZ_BIAS1) { ws[OFF_BIAS1 + i] = hyp_bx[i] + hyp_bh[i]; return; }
    i -= SZ_BIAS1;
    if (i < SZ_ACT1) { ws[OFF_ACT1 + i] = 0.f; return; }
    i -= SZ_ACT1;
    if (i < SZ_C) { ws[OFF_C + i] = 0.f; return; }
    i -= SZ_C;
    if (i < SZ_CH) { ws[OFF_CH + i] = 0.f; return; }
}

// Wcomb[k] = (k<8 ? zw_w[k] @ alpha[k] : zb[k-8] @ zbeta[k-8])  (256 x 1024)
__global__ __launch_bounds__(128) void k_prep_wcomb(
    const float* __restrict__ zw_w, const float* __restrict__ zb,
    const float* __restrict__ alpha, const float* __restrict__ zbeta,
    float* __restrict__ ws)
{
    int kk = blockIdx.z;
    const float* A = (kk < 8) ? (zw_w + (size_t)kk*65536) : (zb + (size_t)(kk-8)*65536);
    const float* Bm = (kk < 8) ? (alpha + (size_t)kk*262144) : (zbeta + (size_t)(kk-8)*262144);
    gemm_dev(A, 256, KSPLIT_NONE, A, 256,
             Bm, 1024, /*b_nk=*/0, /*bias=*/nullptr,
             ws + OFF_WCOMB + (size_t)kk*262144, 1024,
             /*K=*/256, /*k0=*/0, blockIdx.x, blockIdx.y);
}

// bcomb[k, n] = sum_p zw_b[k,p] * alpha[k,p,n]   (k<8)
__global__ __launch_bounds__(256) void k_prep_bcomb(
    const float* __restrict__ zw_b, const float* __restrict__ alpha,
    float* __restrict__ ws)
{
    int k = blockIdx.x;               // 0..7
    int n = blockIdx.y*256 + threadIdx.x;  // 0..1023
    float s = 0.f;
    for (int p=0;p<256;++p)
        s += zw_b[k*256+p] * alpha[(size_t)k*262144 + (size_t)p*1024 + n];
    ws[OFF_BCOMB + (size_t)k*1024 + n] = s;
}

// ---------------- per-step GEMM kernels ----------------
// hyper gates, split-K=4: gpart[sp] = [xt|h|hh](k in sp*384..) @ Wcat1^T
__global__ __launch_bounds__(128) void k_gemmA(
    const float* __restrict__ xt, float* __restrict__ ws)
{
    int sp = blockIdx.z;
    gemm_dev(xt, 256, /*ksplit=*/256, ws + OFF_ACT1, 1280,
             ws + OFF_WCAT1, 1536, /*b_nk=*/1, nullptr,
             ws + OFF_GPART + (size_t)sp*BATCH*1024, 1024,
             /*K=*/384, /*k0=*/sp*384, blockIdx.x, blockIdx.y);
}

// fused: sel0 = xg (xt@Wx^T), sel1 = hg (h@Wh^T), sel2..13 = sc_badj[k] = hyp@Wcomb[k] (+bcomb)
__global__ __launch_bounds__(128) void k_gemmCD(
    const float* __restrict__ xt,
    const float* __restrict__ Wx, const float* __restrict__ Wh,
    float* __restrict__ ws)
{
    int sel = blockIdx.z;
    if (sel == 0) {
        gemm_dev(xt, 256, KSPLIT_NONE, xt, 256,
                 Wx, 256, 1, nullptr,
                 ws + OFF_XGHG, 4096, 256, 0, blockIdx.x, blockIdx.y);
    } else if (sel == 1) {
        gemm_dev(ws + OFF_ACT1, 1280, KSPLIT_NONE, ws + OFF_ACT1, 1280,
                 Wh, 1024, 1, nullptr,
                 ws + OFF_XGHG + (size_t)BATCH*4096, 4096, 1024, 0, blockIdx.x, blockIdx.y);
    } else {
        if (blockIdx.y >= 16) return;
        int kk = sel - 2;  // 0..11
        const float* bias = (kk < 8) ? (ws + OFF_BCOMB + (size_t)kk*1024) : nullptr;
        gemm_dev(ws + OFF_ACT1 + 1024, 1280, KSPLIT_NONE, ws + OFF_ACT1 + 1024, 1280,
                 ws + OFF_WCOMB + (size_t)kk*262144, 1024, 0, bias,
                 ws + OFF_SCB + (size_t)kk*BATCH*1024, 1024, 256, 0, blockIdx.x, blockIdx.y);
    }
}

// ---------------- pointwise cell kernels ----------------
__device__ __forceinline__ void breduce2(float& a, float& b, volatile float* buf, int tid){
    #pragma unroll
    for (int off = 32; off > 0; off >>= 1) {
        a += __shfl_xor(a, off);
        b += __shfl_xor(b, off);
    }
    __syncthreads();                       // protect buf from previous use
    if ((tid & 63) == 0) { buf[(tid>>6)*2] = a; buf[(tid>>6)*2+1] = b; }
    __syncthreads();
    a = buf[0] + buf[2] + buf[4] + buf[6];
    b = buf[1] + buf[3] + buf[5] + buf[7];
}

// hyper LSTM cell: sums split-K partials + bias, 4x LN(256), cell update, LN(ch), writes hyp into act1
__global__ __launch_bounds__(256) void k_hyper_cell(
    const float* __restrict__ lna_g, const float* __restrict__ lna_b,
    const float* __restrict__ ln_g, const float* __restrict__ ln_b,
    float* __restrict__ ws)
{
    __shared__ float buf[8];
    const float* gpart = ws + OFF_GPART;
    float* ch = ws + OFF_CH;
    int b = blockIdx.x, tid = threadIdx.x;
    float v[4];
    #pragma unroll
    for (int g=0; g<4; ++g){
        int idx = b*1024 + g*256 + tid;
        v[g] = gpart[idx] + gpart[131072 + idx] + gpart[262144 + idx] + gpart[393216 + idx]
             + ws[OFF_BIAS1 + g*256 + tid];
    }
    #pragma unroll
    for (int g=0; g<4; ++g){
        float s = v[g], ss = v[g]*v[g];
        breduce2(s, ss, buf, tid);
        float m = s * (1.f/256.f);
        float var = ss * (1.f/256.f) - m*m;
        float rs = rsqrtf(var + EPS);
        v[g] = (v[g]-m)*rs*lna_g[g*256+tid] + lna_b[g*256+tid];
    }
    // gate order (hyper): i, f, g, o
    float chp = ch[b*256 + tid];
    float cn = sigm(v[1])*chp + sigm(v[0])*tanhf(v[2]);
    float s = cn, ss = cn*cn;
    breduce2(s, ss, buf, tid);
    float m = s*(1.f/256.f);
    float var = ss*(1.f/256.f) - m*m;
    float hn = sigm(v[3]) * tanhf((cn-m)*rsqrtf(var + EPS)*ln_g[tid] + ln_b[tid]);
    ch[b*256 + tid] = cn;
    ws[OFF_ACT1 + b*1280 + 1024 + tid] = hn;   // hyp == next hh
}

// main LSTM cell: gates = sc*xg + sc'*hg + b + badj; 4x LN(1024); cell; LN(c); h into act1
__global__ __launch_bounds__(256) void k_main_cell(
    const float* __restrict__ bias4,
    const float* __restrict__ lna_g, const float* __restrict__ lna_b,
    const float* __restrict__ ln_g, const float* __restrict__ ln_b,
    float* __restrict__ ws)
{
    __shared__ float buf[8];
    const float* xghg = ws + OFF_XGHG;
    const float* scb  = ws + OFF_SCB;
    float* c = ws + OFF_C;
    int b = blockIdx.x, tid = threadIdx.x;
    float gn[4][4];
    #pragma unroll
    for (int k=0;k<4;++k){
        float pre[4]; float s=0.f, ss=0.f;
        #pragma unroll
        for (int j=0;j<4;++j){
            int h = j*256 + tid;
            int n = k*1024 + h;
            int bh = b*1024 + h;
            float xgv = xghg[b*4096 + n];
            float hgv = xghg[524288 + b*4096 + n];
            float p = scb[k*131072 + bh]*xgv + scb[(4+k)*131072 + bh]*hgv
                    + bias4[n] + scb[(8+k)*131072 + bh];
            pre[j] = p; s += p; ss += p*p;
        }
        breduce2(s, ss, buf, tid);
        float m = s*(1.f/1024.f);
        float var = ss*(1.f/1024.f) - m*m;
        float rs = rsqrtf(var + EPS);
        #pragma unroll
        for (int j=0;j<4;++j){
            int h=j*256+tid, n=k*1024+h;
            gn[k][j] = (pre[j]-m)*rs*lna_g[n] + lna_b[n];
        }
    }
    // gate order (main): i, j, f, o
    float cnv[4]; float s=0.f, ss=0.f;
    #pragma unroll
    for (int j=0;j<4;++j){
        int h=j*256+tid;
        float cv = c[b*1024+h];
        float x = sigm(gn[2][j])*cv + sigm(gn[0][j])*tanhf(gn[1][j]);
        cnv[j]=x; s+=x; ss+=x*x;
    }
    breduce2(s, ss, buf, tid);
    float m=s*(1.f/1024.f);
    float var=ss*(1.f/1024.f)-m*m;
    float rs=rsqrtf(var + EPS);
    #pragma unroll
    for (int j=0;j<4;++j){
        int h=j*256+tid;
        float hv = sigm(gn[3][j])*tanhf((cnv[j]-m)*rs*ln_g[h] + ln_b[h]);
        c[b*1024+h] = cnv[j];
        ws[OFF_ACT1 + b*1280 + h] = hv;
    }
}

// ---------------- final FC ----------------
__global__ __launch_bounds__(128) void k_fc(
    const float* __restrict__ fcW, const float* __restrict__ fcb,
    const float* __restrict__ ws, float* __restrict__ out)
{
    int b = blockIdx.x, o = threadIdx.x;
    const float* h = ws + OFF_ACT1 + (size_t)b*1280;
    float s = fcb[o];
    for (int k=0;k<1024;++k) s += h[k]*fcW[(size_t)o*1024 + k];
    out[b*OUTN + o] = s;
}

// ---------------- launch ----------------
extern "C" void kernel_launch(void* const* d_in, const int* in_sizes, int n_in,
                              void* d_out, int out_size, void* d_ws, size_t ws_size,
                              hipStream_t stream)
{
    const float* x        = (const float*)d_in[0];   // (512,128,256)
    const float* Wx       = (const float*)d_in[1];   // (4096,256)
    const float* Wh       = (const float*)d_in[2];   // (4096,1024)
    const float* bias     = (const float*)d_in[3];   // (4096)
    const float* lna_g    = (const float*)d_in[4];
    const float* lna_b    = (const float*)d_in[5];
    const float* ln_g     = (const float*)d_in[6];
    const float* ln_b     = (const float*)d_in[7];
    const float* zb       = (const float*)d_in[8];   // (4,256,256)
    const float* zbeta    = (const float*)d_in[9];   // (4,256,1024)
    const float* zw_w     = (const float*)d_in[10];  // (8,256,256)
    const float* zw_b     = (const float*)d_in[11];  // (8,256)
    const float* alpha    = (const float*)d_in[12];  // (8,256,1024)
    const float* hyp_Wx   = (const float*)d_in[13];  // (1024,1280)
    const float* hyp_bx   = (const float*)d_in[14];
    const float* hyp_Wh   = (const float*)d_in[15];  // (1024,256)
    const float* hyp_bh   = (const float*)d_in[16];
    const float* hlna_g   = (const float*)d_in[17];
    const float* hlna_b   = (const float*)d_in[18];
    const float* hln_g    = (const float*)d_in[19];
    const float* hln_b    = (const float*)d_in[20];
    const float* fcW      = (const float*)d_in[21];  // (128,1024)
    const float* fcb      = (const float*)d_in[22];
    float* ws  = (float*)d_ws;
    float* out = (float*)d_out;

    // ---- prep (every call; ws is re-poisoned by harness) ----
    {
        int total = SZ_WCAT1 + SZ_BIAS1 + SZ_ACT1 + SZ_C + SZ_CH;
        int nb = (total + 255)/256;
        k_prep_misc<<<nb, 256, 0, stream>>>(hyp_Wx, hyp_Wh, hyp_bx, hyp_bh, ws);
    }
    k_prep_wcomb<<<dim3(8,16,12), 128, 0, stream>>>(zw_w, zb, alpha, zbeta, ws);
    k_prep_bcomb<<<dim3(8,4), 256, 0, stream>>>(zw_b, alpha, ws);

    // ---- 512 sequential steps ----
    for (int t = 0; t < T_STEPS; ++t) {
        const float* xt = x + (size_t)t*BATCH*DIN;
        k_gemmA<<<dim3(4,16,4), 128, 0, stream>>>(xt, ws);
        k_hyper_cell<<<BATCH, 256, 0, stream>>>(hlna_g, hlna_b, hln_g, hln_b, ws);
        k_gemmCD<<<dim3(4,64,14), 128, 0, stream>>>(xt, Wx, Wh, ws);
        k_main_cell<<<BATCH, 256, 0, stream>>>(bias, lna_g, lna_b, ln_g, ln_b, ws);
    }

    // ---- final projection ----
    k_fc<<<BATCH, 128, 0, stream>>>(fcW, fcb, ws, out);
}

// Round 2
// 34194.025 us; speedup vs baseline: 2.0785x; 2.0785x over previous
//
#include <hip/hip_runtime.h>
#include <math.h>

// ---------------- problem dims ----------------
#define T_STEPS 512
#define BATCH   128
#define DIN     256
#define HMAIN   1024
#define HHYP    256
#define OUTN    128
#define EPS     1e-3f

#define KSPLIT_NONE (1<<30)

typedef __attribute__((ext_vector_type(4))) float f32x4;
typedef __attribute__((ext_vector_type(8))) short s16x8;

__device__ __forceinline__ float sigm(float x){ return 1.f/(1.f + expf(-x)); }

__device__ __forceinline__ unsigned short f2bf(float f){
    union { float f; unsigned u; } x; x.f = f;
    unsigned r = x.u + 0x7FFFu + ((x.u >> 16) & 1u);   // RNE
    return (unsigned short)(r >> 16);
}

// =====================================================================
// fp32 tiled GEMM (prep only): tile 32x64, KT=32, 128 thr, 4x4 micro
// =====================================================================
#define BM 32
#define BN 64
#define KT 32
__device__ void gemm_dev(const float* __restrict__ A1, int lda1, int ksplit,
                         const float* __restrict__ A2, int lda2,
                         const float* __restrict__ Bp, int ldb, int b_nk,
                         const float* __restrict__ bias,
                         float* __restrict__ C, int ldc,
                         int K, int k0, int mtile, int ntile)
{
    __shared__ __align__(16) float As[KT][BM+4];
    __shared__ __align__(16) float Bs[KT][BN+4];
    const int tid = threadIdx.x;
    const int mt = tid >> 4, nt = tid & 15;
    const int m0g = mtile*BM, n0g = ntile*BN;
    float acc[4][4];
    #pragma unroll
    for (int i=0;i<4;++i) { acc[i][0]=0;acc[i][1]=0;acc[i][2]=0;acc[i][3]=0; }
    for (int kt = 0; kt < K; kt += KT) {
        __syncthreads();
        #pragma unroll
        for (int i=0;i<8;++i){
            int e = tid + i*128;
            int m = e >> 5, k = e & 31;
            int gk = k0 + kt + k, gm = m0g + m;
            float v = (gk < ksplit) ? A1[(size_t)gm*lda1 + gk]
                                    : A2[(size_t)gm*lda2 + (gk - ksplit)];
            As[k][m] = v;
        }
        if (b_nk) {
            #pragma unroll
            for (int i=0;i<16;++i){
                int e = tid + i*128;
                int n = e >> 5, k = e & 31;
                Bs[k][n] = Bp[(size_t)(n0g + n)*ldb + (k0 + kt + k)];
            }
        } else {
            #pragma unroll
            for (int i=0;i<16;++i){
                int e = tid + i*128;
                int k = e >> 6, n = e & 63;
                Bs[k][n] = Bp[(size_t)(k0 + kt + k)*ldb + (n0g + n)];
            }
        }
        __syncthreads();
        #pragma unroll
        for (int k=0;k<KT;++k){
            float4 av = *(const float4*)(&As[k][4*mt]);
            float4 bv = *(const float4*)(&Bs[k][4*nt]);
            acc[0][0]+=av.x*bv.x; acc[0][1]+=av.x*bv.y; acc[0][2]+=av.x*bv.z; acc[0][3]+=av.x*bv.w;
            acc[1][0]+=av.y*bv.x; acc[1][1]+=av.y*bv.y; acc[1][2]+=av.y*bv.z; acc[1][3]+=av.y*bv.w;
            acc[2][0]+=av.z*bv.x; acc[2][1]+=av.z*bv.y; acc[2][2]+=av.z*bv.z; acc[2][3]+=av.z*bv.w;
            acc[3][0]+=av.w*bv.x; acc[3][1]+=av.w*bv.y; acc[3][2]+=av.w*bv.z; acc[3][3]+=av.w*bv.w;
        }
    }
    #pragma unroll
    for (int i=0;i<4;++i){
        int gm = m0g + 4*mt + i;
        #pragma unroll
        for (int j=0;j<4;++j){
            int gn = n0g + 4*nt + j;
            float v = acc[i][j];
            if (bias) v += bias[gn];
            C[(size_t)gm*ldc + gn] = v;
        }
    }
}

// =====================================================================
// bf16 MFMA GEMM: block tile 32(M) x 128(N), KT=32, 256 thr (4 waves)
// wave w: rows [(w>>1)*16, +16), cols [(w&1)*64, +64) = 4 mfma tiles
// A fp32 in global (converted to bf16 on load); B bf16 (N,K) layout.
// =====================================================================
#define ASTR 40   // LDS row stride (bf16 elems): 32 + 8 pad
__device__ void gemm_mfma(const float* __restrict__ A1, int lda1, int ksplit,
                          const float* __restrict__ A2, int lda2,
                          const unsigned short* __restrict__ B, int ldb,
                          const float* __restrict__ bias,
                          float* __restrict__ C, int ldc,
                          int K, int k0, int mtile, int ntile)
{
    __shared__ __align__(16) unsigned short As[32*ASTR];
    __shared__ __align__(16) unsigned short Bs[128*ASTR];
    const int tid = threadIdx.x;
    const int lane = tid & 63, w = tid >> 6;
    const int wm = (w >> 1) * 16, wn = (w & 1) * 64;
    const int fr = lane & 15, koff = (lane >> 4) * 8;
    const int m0g = mtile*32, n0g = ntile*128;

    f32x4 acc[4];
    #pragma unroll
    for (int j=0;j<4;++j) acc[j] = (f32x4){0.f,0.f,0.f,0.f};

    // loader indices
    const int arow = tid >> 3, akc = (tid & 7) * 4;           // A: 1 x 4-elem chunk
    for (int kt = 0; kt < K; kt += 32) {
        __syncthreads();
        {   // A tile: 32 rows x 32 k, fp32 -> bf16
            int gk = k0 + kt + akc;
            int gm = m0g + arow;
            const float* src = (gk < ksplit) ? (A1 + (size_t)gm*lda1 + gk)
                                             : (A2 + (size_t)gm*lda2 + (gk - ksplit));
            float4 v = *(const float4*)src;
            unsigned short* d = &As[arow*ASTR + akc];
            d[0] = f2bf(v.x); d[1] = f2bf(v.y); d[2] = f2bf(v.z); d[3] = f2bf(v.w);
        }
        #pragma unroll
        for (int i=0;i<4;++i){   // B tile: 128 rows x 32 k, bf16 direct
            int e = tid + i*256;
            int n = e >> 3, kc = (e & 7) * 4;
            ushort4 bv = *(const ushort4*)(B + (size_t)(n0g + n)*ldb + (k0 + kt + kc));
            unsigned short* d = &Bs[n*ASTR + kc];
            d[0] = bv.x; d[1] = bv.y; d[2] = bv.z; d[3] = bv.w;
        }
        __syncthreads();
        s16x8 af = *(const s16x8*)&As[(wm + fr)*ASTR + koff];
        #pragma unroll
        for (int j=0;j<4;++j){
            s16x8 bf = *(const s16x8*)&Bs[(wn + j*16 + fr)*ASTR + koff];
            acc[j] = __builtin_amdgcn_mfma_f32_16x16x32_bf16(af, bf, acc[j], 0, 0, 0);
        }
    }
    #pragma unroll
    for (int j=0;j<4;++j){
        int gn = n0g + wn + j*16 + fr;
        float bb = bias ? bias[gn] : 0.f;
        #pragma unroll
        for (int r=0;r<4;++r){
            int gm = m0g + wm + (lane >> 4)*4 + r;
            C[(size_t)gm*ldc + gn] = acc[j][r] + bb;
        }
    }
}

// =====================================================================
// prep kernels
// =====================================================================
__global__ __launch_bounds__(256) void k_prep_convert(
    const float* __restrict__ hyp_Wx, const float* __restrict__ hyp_Wh,
    const float* __restrict__ hyp_bx, const float* __restrict__ hyp_bh,
    const float* __restrict__ Wx, const float* __restrict__ Wh,
    unsigned short* __restrict__ wcat1bf, unsigned short* __restrict__ wxbf,
    unsigned short* __restrict__ whbf, float* __restrict__ bias1,
    float* __restrict__ act1, float* __restrict__ c, float* __restrict__ ch)
{
    size_t i = (size_t)blockIdx.x*256 + threadIdx.x;
    if (i < 1572864u) {   // Wcat1 = [hyp_Wx | hyp_Wh], (1024,1536)
        int n = (int)(i / 1536), k = (int)(i % 1536);
        float v = (k < 1280) ? hyp_Wx[(size_t)n*1280 + k] : hyp_Wh[(size_t)n*256 + (k-1280)];
        wcat1bf[i] = f2bf(v); return;
    }
    i -= 1572864u;
    if (i < 1048576u) { wxbf[i] = f2bf(Wx[i]); return; }
    i -= 1048576u;
    if (i < 4194304u) { whbf[i] = f2bf(Wh[i]); return; }
    i -= 4194304u;
    if (i < 1024u) { bias1[i] = hyp_bx[i] + hyp_bh[i]; return; }
    i -= 1024u;
    if (i < 163840u) { act1[i] = 0.f; return; }
    i -= 163840u;
    if (i < 131072u) { c[i] = 0.f; return; }
    i -= 131072u;
    if (i < 32768u) { ch[i] = 0.f; return; }
}

// Wcomb f32: (k<8 ? zw_w[k]@alpha[k] : zb[k-8]@zbeta[k-8])  (256 x 1024)
__global__ __launch_bounds__(128) void k_prep_wcomb(
    const float* __restrict__ zw_w, const float* __restrict__ zb,
    const float* __restrict__ alpha, const float* __restrict__ zbeta,
    float* __restrict__ wcombf32)
{
    int kk = blockIdx.z;
    const float* A = (kk < 8) ? (zw_w + (size_t)kk*65536) : (zb + (size_t)(kk-8)*65536);
    const float* Bm = (kk < 8) ? (alpha + (size_t)kk*262144) : (zbeta + (size_t)(kk-8)*262144);
    gemm_dev(A, 256, KSPLIT_NONE, A, 256, Bm, 1024, 0, nullptr,
             wcombf32 + (size_t)kk*262144, 1024, 256, 0, blockIdx.x, blockIdx.y);
}

// transpose+convert: wcombbf[kk][n][k] = bf16(wcombf32[kk][k][n])
__global__ __launch_bounds__(256) void k_prep_cvtcomb(
    const float* __restrict__ wcombf32, unsigned short* __restrict__ wcombbf)
{
    size_t i = (size_t)blockIdx.x*256 + threadIdx.x;
    if (i >= 3145728u) return;
    int kk = (int)(i / 262144u);
    int r  = (int)(i % 262144u);
    int n = r / 256, k = r % 256;
    wcombbf[i] = f2bf(wcombf32[(size_t)kk*262144 + (size_t)k*1024 + n]);
}

__global__ __launch_bounds__(256) void k_prep_bcomb(
    const float* __restrict__ zw_b, const float* __restrict__ alpha,
    float* __restrict__ bcomb)
{
    int k = blockIdx.x;
    int n = blockIdx.y*256 + threadIdx.x;
    float s = 0.f;
    for (int p=0;p<256;++p)
        s += zw_b[k*256+p] * alpha[(size_t)k*262144 + (size_t)p*1024 + n];
    bcomb[(size_t)k*1024 + n] = s;
}

// =====================================================================
// step kernel 1: hyper gates (split-K 4) + xg + hg      [384 blocks]
// =====================================================================
__global__ __launch_bounds__(256) void k_step1(
    const float* __restrict__ xt, const float* __restrict__ act1,
    const unsigned short* __restrict__ wcat1bf,
    const unsigned short* __restrict__ wxbf, const unsigned short* __restrict__ whbf,
    float* __restrict__ gpart, float* __restrict__ xghg)
{
    int bid = blockIdx.x;
    if (bid < 128) {          // hyper gates: [xt|h|hh] @ Wcat1^T, split-K 4
        int sp = bid >> 5, r = bid & 31;
        gemm_mfma(xt, 256, 256, act1, 1280, wcat1bf, 1536, nullptr,
                  gpart + (size_t)sp*131072, 1024, 384, sp*384, r >> 3, r & 7);
    } else if (bid < 256) {   // xg = xt @ Wx^T  (128 x 4096, K=256)
        int r = bid - 128;
        gemm_mfma(xt, 256, KSPLIT_NONE, xt, 256, wxbf, 256, nullptr,
                  xghg, 4096, 256, 0, r >> 5, r & 31);
    } else {                  // hg = h @ Wh^T   (128 x 4096, K=1024)
        int r = bid - 256;
        gemm_mfma(act1, 1280, KSPLIT_NONE, act1, 1280, whbf, 1024, nullptr,
                  xghg + 524288, 4096, 1024, 0, r >> 5, r & 31);
    }
}

// =====================================================================
// step kernel 2: 12 x (hyp @ Wcomb[k]) (+bcomb)          [384 blocks]
// =====================================================================
__global__ __launch_bounds__(256) void k_step2(
    const float* __restrict__ act1, const unsigned short* __restrict__ wcombbf,
    const float* __restrict__ bcomb, float* __restrict__ scb)
{
    int bid = blockIdx.x;
    int kk = bid >> 5, r = bid & 31;
    const float* bias = (kk < 8) ? (bcomb + (size_t)kk*1024) : nullptr;
    gemm_mfma(act1 + 1024, 1280, KSPLIT_NONE, act1 + 1024, 1280,
              wcombbf + (size_t)kk*262144, 256, bias,
              scb + (size_t)kk*131072, 1024, 256, 0, r >> 3, r & 7);
}

// =====================================================================
// pointwise cells
// =====================================================================
__device__ __forceinline__ void breduce2(float& a, float& b, volatile float* buf, int tid){
    #pragma unroll
    for (int off = 32; off > 0; off >>= 1) { a += __shfl_xor(a, off); b += __shfl_xor(b, off); }
    __syncthreads();
    if ((tid & 63) == 0) { buf[(tid>>6)*2] = a; buf[(tid>>6)*2+1] = b; }
    __syncthreads();
    a = buf[0] + buf[2] + buf[4] + buf[6];
    b = buf[1] + buf[3] + buf[5] + buf[7];
}

__global__ __launch_bounds__(256) void k_hyper_cell(
    const float* __restrict__ lna_g, const float* __restrict__ lna_b,
    const float* __restrict__ ln_g, const float* __restrict__ ln_b,
    const float* __restrict__ gpart, const float* __restrict__ bias1,
    float* __restrict__ ch, float* __restrict__ act1)
{
    __shared__ float buf[8];
    int b = blockIdx.x, tid = threadIdx.x;
    float v[4];
    #pragma unroll
    for (int g=0; g<4; ++g){
        int idx = b*1024 + g*256 + tid;
        v[g] = gpart[idx] + gpart[131072 + idx] + gpart[262144 + idx] + gpart[393216 + idx]
             + bias1[g*256 + tid];
    }
    #pragma unroll
    for (int g=0; g<4; ++g){
        float s = v[g], ss = v[g]*v[g];
        breduce2(s, ss, buf, tid);
        float m = s * (1.f/256.f);
        float var = ss * (1.f/256.f) - m*m;
        v[g] = (v[g]-m)*rsqrtf(var + EPS)*lna_g[g*256+tid] + lna_b[g*256+tid];
    }
    float chp = ch[b*256 + tid];
    float cn = sigm(v[1])*chp + sigm(v[0])*tanhf(v[2]);
    float s = cn, ss = cn*cn;
    breduce2(s, ss, buf, tid);
    float m = s*(1.f/256.f);
    float var = ss*(1.f/256.f) - m*m;
    float hn = sigm(v[3]) * tanhf((cn-m)*rsqrtf(var + EPS)*ln_g[tid] + ln_b[tid]);
    ch[b*256 + tid] = cn;
    act1[b*1280 + 1024 + tid] = hn;
}

__global__ __launch_bounds__(256) void k_main_cell(
    const float* __restrict__ bias4,
    const float* __restrict__ lna_g, const float* __restrict__ lna_b,
    const float* __restrict__ ln_g, const float* __restrict__ ln_b,
    const float* __restrict__ xghg, const float* __restrict__ scb,
    float* __restrict__ c, float* __restrict__ act1)
{
    __shared__ float buf[8];
    int b = blockIdx.x, tid = threadIdx.x;
    float gn[4][4];
    #pragma unroll
    for (int k=0;k<4;++k){
        float pre[4]; float s=0.f, ss=0.f;
        #pragma unroll
        for (int j=0;j<4;++j){
            int h = j*256 + tid;
            int n = k*1024 + h;
            int bh = b*1024 + h;
            float xgv = xghg[b*4096 + n];
            float hgv = xghg[524288 + b*4096 + n];
            float p = scb[k*131072 + bh]*xgv + scb[(4+k)*131072 + bh]*hgv
                    + bias4[n] + scb[(8+k)*131072 + bh];
            pre[j] = p; s += p; ss += p*p;
        }
        breduce2(s, ss, buf, tid);
        float m = s*(1.f/1024.f);
        float var = ss*(1.f/1024.f) - m*m;
        float rs = rsqrtf(var + EPS);
        #pragma unroll
        for (int j=0;j<4;++j){
            int h=j*256+tid, n=k*1024+h;
            gn[k][j] = (pre[j]-m)*rs*lna_g[n] + lna_b[n];
        }
    }
    float cnv[4]; float s=0.f, ss=0.f;
    #pragma unroll
    for (int j=0;j<4;++j){
        int h=j*256+tid;
        float cv = c[b*1024+h];
        float x = sigm(gn[2][j])*cv + sigm(gn[0][j])*tanhf(gn[1][j]);
        cnv[j]=x; s+=x; ss+=x*x;
    }
    breduce2(s, ss, buf, tid);
    float m=s*(1.f/1024.f);
    float var=ss*(1.f/1024.f)-m*m;
    float rs=rsqrtf(var + EPS);
    #pragma unroll
    for (int j=0;j<4;++j){
        int h=j*256+tid;
        float hv = sigm(gn[3][j])*tanhf((cnv[j]-m)*rs*ln_g[h] + ln_b[h]);
        c[b*1024+h] = cnv[j];
        act1[b*1280 + h] = hv;
    }
}

__global__ __launch_bounds__(128) void k_fc(
    const float* __restrict__ fcW, const float* __restrict__ fcb,
    const float* __restrict__ act1, float* __restrict__ out)
{
    int b = blockIdx.x, o = threadIdx.x;
    const float* h = act1 + (size_t)b*1280;
    float s = fcb[o];
    for (int k=0;k<1024;++k) s += h[k]*fcW[(size_t)o*1024 + k];
    out[b*OUTN + o] = s;
}

// =====================================================================
// launch
// =====================================================================
extern "C" void kernel_launch(void* const* d_in, const int* in_sizes, int n_in,
                              void* d_out, int out_size, void* d_ws, size_t ws_size,
                              hipStream_t stream)
{
    const float* x        = (const float*)d_in[0];
    const float* Wx       = (const float*)d_in[1];
    const float* Wh       = (const float*)d_in[2];
    const float* bias     = (const float*)d_in[3];
    const float* lna_g    = (const float*)d_in[4];
    const float* lna_b    = (const float*)d_in[5];
    const float* ln_g     = (const float*)d_in[6];
    const float* ln_b     = (const float*)d_in[7];
    const float* zb       = (const float*)d_in[8];
    const float* zbeta    = (const float*)d_in[9];
    const float* zw_w     = (const float*)d_in[10];
    const float* zw_b     = (const float*)d_in[11];
    const float* alpha    = (const float*)d_in[12];
    const float* hyp_Wx   = (const float*)d_in[13];
    const float* hyp_bx   = (const float*)d_in[14];
    const float* hyp_Wh   = (const float*)d_in[15];
    const float* hyp_bh   = (const float*)d_in[16];
    const float* hlna_g   = (const float*)d_in[17];
    const float* hlna_b   = (const float*)d_in[18];
    const float* hln_g    = (const float*)d_in[19];
    const float* hln_b    = (const float*)d_in[20];
    const float* fcW      = (const float*)d_in[21];
    const float* fcb      = (const float*)d_in[22];
    float* out = (float*)d_out;

    // ---- workspace carve-up (bytes) ----
    unsigned short* wcat1bf = (unsigned short*)d_ws;          // 1024*1536
    unsigned short* wxbf    = wcat1bf + 1572864;              // 4096*256
    unsigned short* whbf    = wxbf + 1048576;                 // 4096*1024
    unsigned short* wcombbf = whbf + 4194304;                 // 12*1024*256
    float* bcomb = (float*)(wcombbf + 3145728);               // 8*1024
    float* bias1 = bcomb + 8192;                              // 1024
    float* act1  = bias1 + 1024;                              // 128*1280 [h|hh] f32
    float* c     = act1 + 163840;                             // 128*1024
    float* ch    = c + 131072;                                // 128*256
    float* stepbuf = ch + 32768;                              // 3,145,728 floats
    float* gpart = stepbuf;                                   // 4*128*1024
    float* scb   = gpart + 524288;                            // 12*128*1024
    float* xghg  = scb + 1572864;                             // 2*128*4096
    float* wcombf32 = stepbuf;                                // prep-time alias

    // ---- prep ----
    k_prep_convert<<<(7144448 + 255)/256, 256, 0, stream>>>(
        hyp_Wx, hyp_Wh, hyp_bx, hyp_bh, Wx, Wh,
        wcat1bf, wxbf, whbf, bias1, act1, c, ch);
    k_prep_wcomb<<<dim3(8,16,12), 128, 0, stream>>>(zw_w, zb, alpha, zbeta, wcombf32);
    k_prep_bcomb<<<dim3(8,4), 256, 0, stream>>>(zw_b, alpha, bcomb);
    k_prep_cvtcomb<<<(3145728 + 255)/256, 256, 0, stream>>>(wcombf32, wcombbf);

    // ---- 512 sequential steps ----
    for (int t = 0; t < T_STEPS; ++t) {
        const float* xt = x + (size_t)t*BATCH*DIN;
        k_step1<<<384, 256, 0, stream>>>(xt, act1, wcat1bf, wxbf, whbf, gpart, xghg);
        k_hyper_cell<<<BATCH, 256, 0, stream>>>(hlna_g, hlna_b, hln_g, hln_b,
                                                gpart, bias1, ch, act1);
        k_step2<<<384, 256, 0, stream>>>(act1, wcombbf, bcomb, scb);
        k_main_cell<<<BATCH, 256, 0, stream>>>(bias, lna_g, lna_b, ln_g, ln_b,
                                               xghg, scb, c, act1);
    }

    // ---- final projection ----
    k_fc<<<BATCH, 128, 0, stream>>>(fcW, fcb, act1, out);
}